// Round 7
// baseline (585.265 us; speedup 1.0000x reference)
//
#include <hip/hip_runtime.h>
#include <math.h>

#define NB 2
#define NN1 4096
#define NN2 8192
#define NPART 16
#define PARTSZ (NN2 / NPART)     // 512
#define NCHUNK (PARTSZ / 128)    // 4
#define LEAKK 0.1f
#define GPAD 68

typedef unsigned long long u64k;

__device__ __forceinline__ float leaky_(float x) { return fmaxf(x, LEAKK * x); }
__device__ __forceinline__ float sigm_(float x) { return 1.0f / (1.0f + __expf(-x)); }

// branchless stable sorted-insert of (d,i) into ascending 8-list (f32 + idx).
// Strict compares => equal keys keep the earlier (lower-idx within a thread) entry.
__device__ __forceinline__ void insfi_(float d, int i, float* q, int* qi) {
  bool c0 = d < q[0], c1 = d < q[1], c2 = d < q[2], c3 = d < q[3];
  bool c4 = d < q[4], c5 = d < q[5], c6 = d < q[6], c7 = d < q[7];
  q[7] = fminf(fmaxf(d, q[6]), q[7]);  qi[7] = c6 ? qi[6] : (c7 ? i : qi[7]);
  q[6] = fminf(fmaxf(d, q[5]), q[6]);  qi[6] = c5 ? qi[5] : (c6 ? i : qi[6]);
  q[5] = fminf(fmaxf(d, q[4]), q[5]);  qi[5] = c4 ? qi[4] : (c5 ? i : qi[5]);
  q[4] = fminf(fmaxf(d, q[3]), q[4]);  qi[4] = c3 ? qi[3] : (c4 ? i : qi[4]);
  q[3] = fminf(fmaxf(d, q[2]), q[3]);  qi[3] = c2 ? qi[2] : (c3 ? i : qi[3]);
  q[2] = fminf(fmaxf(d, q[1]), q[2]);  qi[2] = c1 ? qi[1] : (c2 ? i : qi[2]);
  q[1] = fminf(fmaxf(d, q[0]), q[1]);  qi[1] = c0 ? qi[0] : (c1 ? i : qi[1]);
  q[0] = fminf(d, q[0]);               qi[0] = c0 ? i : qi[0];
}

// monotone f32 -> orderable u32 (handles negatives), packed with idx for lex order
__device__ __forceinline__ u64k packdi_(float d, int i) {
  unsigned b = __float_as_uint(d);
  b ^= (unsigned)(((int)b >> 31)) | 0x80000000u;
  return ((u64k)b << 32) | (unsigned)i;
}

// merge two sorted-ascending 8-lists, keep smallest 8 in a
__device__ __forceinline__ void merge8q_(u64k* a, u64k* b) {
  u64k r[8];
#pragma unroll
  for (int s = 0; s < 8; ++s) {
    bool ta = a[0] < b[0];
    r[s] = ta ? a[0] : b[0];
#pragma unroll
    for (int j = 0; j < 7; ++j) {
      a[j] = ta ? a[j + 1] : a[j];
      b[j] = ta ? b[j] : b[j + 1];
    }
  }
#pragma unroll
  for (int j = 0; j < 8; ++j) a[j] = r[j];
}

// ---------------- K0: transpose all 15 weight matrices into ws ----------------
__global__ void prep_w_kernel(const float* s0, const float* s1, const float* s2,
                              const float* s3, const float* s4, const float* s5,
                              const float* s6, const float* s7, const float* s8,
                              const float* s9, const float* s10, const float* s11,
                              const float* s12, const float* s13, const float* s14,
                              float* wt) {
  const float* srcs[15] = {s0, s1, s2, s3, s4, s5, s6, s7, s8, s9, s10, s11, s12, s13, s14};
  int bid = blockIdx.x;
  const float* src = srcs[bid];
  int cols = (bid < 6) ? 64 : (((bid - 6) % 3 == 0) ? 3 : 64);
  float* dst = wt + bid * 4096;
  for (int e = threadIdx.x; e < 64 * cols; e += blockDim.x) {
    int o = e / cols, c = e - o * cols;
    dst[c * 64 + o] = src[e];
  }
}

// ------- K1: normalize knn features -> k-major fT[b][k][n]; pack xyz+|x|^2 -------
__global__ __launch_bounds__(256) void prep_side_kernel(const float* knn, const float* xyz,
                                                        float* fT, float* xdst, int N) {
  __shared__ float T[64 * 65];
  __shared__ float ps[4 * 64];
  __shared__ float rsS[64];
  int b = blockIdx.y;
  int n0 = blockIdx.x * 64;
  int t = threadIdx.x, w = t >> 6, l = t & 63;
  const float* kb = knn + (size_t)b * 64 * N + n0;
#pragma unroll
  for (int i = 0; i < 16; ++i) {
    int c = w * 16 + i;
    T[c * 65 + l] = kb[(size_t)c * N + l];
  }
  __syncthreads();
  float s = 0.f;
#pragma unroll
  for (int i = 0; i < 16; ++i) { float v = T[(w * 16 + i) * 65 + l]; s += v * v; }
  ps[w * 64 + l] = s;
  __syncthreads();
  if (t < 64) {
    float rsum = ps[t] + ps[64 + t] + ps[128 + t] + ps[192 + t];
    rsS[t] = 1.0f / sqrtf(rsum + 1e-8f);
    const float* xb = xyz + (size_t)b * 3 * N + n0;
    float x = xb[t], y = xb[N + t], z = xb[2 * N + t];
    ((float4*)xdst)[b * N + n0 + t] = make_float4(x, y, z, x * x + y * y + z * z);
  }
  __syncthreads();
  float rl = rsS[l];
#pragma unroll
  for (int i = 0; i < 16; ++i) {
    int c = w * 16 + i;
    fT[((size_t)b * 64 + c) * N + n0 + l] = T[c * 65 + l] * rl;
  }
}

// ---------------- K2: three fused 1x1 conv matvecs ----------------
__global__ __launch_bounds__(256) void fuse_kernel(const float* pts, const float* wt0,
                                                   const float* wt1, const float* wt2,
                                                   float* d0, float* d1, float* d2, int N) {
  int b = blockIdx.y;
  int w = threadIdx.x >> 6, l = threadIdx.x & 63;
  int n = blockIdx.x * 4 + w;
  const float* pb = pts + (size_t)b * 64 * N + n;
  float a0 = 0.f, a1 = 0.f, a2 = 0.f;
  for (int c = 0; c < 64; ++c) {
    float p = pb[(size_t)c * N];
    a0 += p * wt0[c * 64 + l];
    a1 += p * wt1[c * 64 + l];
    a2 += p * wt2[c * 64 + l];
  }
  size_t ob = (size_t)(b * N + n) * 64 + l;
  d0[ob] = a0; d1[ob] = a1; d2[ob] = a2;
}

// ---------------- K3: dual-metric partitioned KNN (v6: f32+idx selection) -------
__global__ __launch_bounds__(256, 3) void knn_kernel(const float* f1T, const float* f2T,
                                                     const float* x1t, const float* x2t,
                                                     u64k* pq) {
  __shared__ __align__(16) float SH[13120];
  float* f1t = SH;               // 4096  : [k][row]
  float* f2d = SH + 4096;        // 8256  : chunk [k][cand] (k*128+cand) then dtile [r][129]
  float* x1x = SH + 12352;
  float* x1y = SH + 12416;
  float* x1z = SH + 12480;
  float* x1w = SH + 12544;
  float* x2s = SH + 12608;       // 512 : [cand][4]

  int t = threadIdx.x;
  int lane = t & 63, w = t >> 6;
  int n0 = blockIdx.x * 64;
  int part = (int)blockIdx.y;
  int b = (int)blockIdx.z;

  // stage f1 tile from k-major f1T: thread t -> k = t>>2, rows (t&3)*16..+16
  {
    int k = t >> 2, rs0 = (t & 3) * 16;
    const float* src = f1T + ((size_t)b * 64 + k) * NN1 + n0 + rs0;
    float* dst = &f1t[k * 64 + rs0];
#pragma unroll
    for (int p = 0; p < 4; ++p)
      *(float4*)(dst + p * 4) = *(const float4*)(src + p * 4);
    if (t < 64) {
      float4 v = ((const float4*)x1t)[b * NN1 + n0 + t];
      x1x[t] = v.x; x1y[t] = v.y; x1z[t] = v.z; x1w[t] = v.w;
    }
  }

  float cd[8], ed[8]; int ci[8], ei[8];
#pragma unroll
  for (int j = 0; j < 8; ++j) { cd[j] = INFINITY; ed[j] = INFINITY; ci[j] = 0; ei[j] = 0; }

  int ty = t >> 4, tx = t & 15;
  __syncthreads();
  float xx = x1x[lane], xy = x1y[lane], xz = x1z[lane], xw = x1w[lane];

  for (int ch = 0; ch < NCHUNK; ++ch) {
    int cc = part * PARTSZ + ch * 128;

    // stage f2 chunk from k-major f2T: thread t -> k8 = t>>5, cand seg (t&31)*4
    {
      int k8 = t >> 5, cs = (t & 31) * 4;
#pragma unroll
      for (int p = 0; p < 8; ++p) {
        int k = k8 * 8 + p;
        *(float4*)&f2d[k * 128 + cs] =
            *(const float4*)(f2T + ((size_t)b * 64 + k) * NN2 + cc + cs);
      }
      if (t < 128) ((float4*)x2s)[t] = ((const float4*)x2t)[b * NN2 + cc + t];
    }
    __syncthreads();

    // 64x128 similarity tile, 4 rows x 8 cols per thread (split-column)
    float acc0[4][4], acc1[4][4];
#pragma unroll
    for (int i = 0; i < 4; ++i)
#pragma unroll
      for (int j = 0; j < 4; ++j) { acc0[i][j] = 0.f; acc1[i][j] = 0.f; }

#pragma unroll 2
    for (int k = 0; k < 64; ++k) {
      float4 a  = *(const float4*)&f1t[k * 64 + ty * 4];
      float4 b0 = *(const float4*)&f2d[k * 128 + tx * 4];
      float4 b1 = *(const float4*)&f2d[k * 128 + 64 + tx * 4];
      acc0[0][0] += a.x * b0.x; acc0[0][1] += a.x * b0.y; acc0[0][2] += a.x * b0.z; acc0[0][3] += a.x * b0.w;
      acc0[1][0] += a.y * b0.x; acc0[1][1] += a.y * b0.y; acc0[1][2] += a.y * b0.z; acc0[1][3] += a.y * b0.w;
      acc0[2][0] += a.z * b0.x; acc0[2][1] += a.z * b0.y; acc0[2][2] += a.z * b0.z; acc0[2][3] += a.z * b0.w;
      acc0[3][0] += a.w * b0.x; acc0[3][1] += a.w * b0.y; acc0[3][2] += a.w * b0.z; acc0[3][3] += a.w * b0.w;
      acc1[0][0] += a.x * b1.x; acc1[0][1] += a.x * b1.y; acc1[0][2] += a.x * b1.z; acc1[0][3] += a.x * b1.w;
      acc1[1][0] += a.y * b1.x; acc1[1][1] += a.y * b1.y; acc1[1][2] += a.y * b1.z; acc1[1][3] += a.y * b1.w;
      acc1[2][0] += a.z * b1.x; acc1[2][1] += a.z * b1.y; acc1[2][2] += a.z * b1.z; acc1[2][3] += a.z * b1.w;
      acc1[3][0] += a.w * b1.x; acc1[3][1] += a.w * b1.y; acc1[3][2] += a.w * b1.z; acc1[3][3] += a.w * b1.w;
    }
    __syncthreads();

    // write cos distances (1 - dot, unclamped == ref) into dtile[r][c] = f2d[r*129+c]
#pragma unroll
    for (int i = 0; i < 4; ++i) {
      int r = ty * 4 + i;
#pragma unroll
      for (int j = 0; j < 4; ++j) {
        f2d[r * 129 + tx * 4 + j]      = 1.f - acc0[i][j];
        f2d[r * 129 + 64 + tx * 4 + j] = 1.f - acc1[i][j];
      }
    }
    __syncthreads();

    // selection: thread (row=lane, quarter=w) scans cols [w*32, w*32+32)
    {
      const float* drow = &f2d[lane * 129 + w * 32];
      const float4* x2q = ((const float4*)x2s) + w * 32;
#pragma unroll 4
      for (int j = 0; j < 32; ++j) {
        int gi = cc + w * 32 + j;
        insfi_(drow[j], gi, cd, ci);
        float4 xv = x2q[j];
        float d3 = xw + xv.w - 2.f * (xx * xv.x + xy * xv.y + xz * xv.z);
        insfi_(d3, gi, ed, ei);
      }
    }
    __syncthreads();
  }

  // pack to orderable u64 and in-block quarter-merge (alias whole arena)
  {
    u64k* Lc = (u64k*)SH;
    u64k* Le = ((u64k*)SH) + 2112;
#pragma unroll
    for (int j = 0; j < 8; ++j) {
      Lc[lane * 33 + w * 8 + j] = packdi_(cd[j], ci[j]);
      Le[lane * 33 + w * 8 + j] = packdi_(ed[j], ei[j]);
    }
    __syncthreads();
    if (t < 128) {
      int typ = t >> 6, r = t & 63;
      const u64k* L = typ ? Le : Lc;
      u64k a0[8], a1[8], a2[8], a3[8];
#pragma unroll
      for (int j = 0; j < 8; ++j) {
        a0[j] = L[r * 33 + 0 + j];
        a1[j] = L[r * 33 + 8 + j];
        a2[j] = L[r * 33 + 16 + j];
        a3[j] = L[r * 33 + 24 + j];
      }
      merge8q_(a0, a1);
      merge8q_(a2, a3);
      merge8q_(a0, a2);
      size_t base = ((size_t)((b * NPART + part) * NN1) + n0 + r) * 16 + typ * 8;
#pragma unroll
      for (int j = 0; j < 8; ++j) pq[base + j] = a0[j];
    }
  }
}

// ---------------- K4: merge the NPART partial lists -> final idx ----------------
__device__ __forceinline__ void loadq_(const u64k* pq, int b, int p, int n1, int typ, u64k* q) {
  size_t base = ((size_t)((b * NPART + p) * NN1) + n1) * 16 + typ * 8;
#pragma unroll
  for (int j = 0; j < 8; ++j) q[j] = pq[base + j];
}

__global__ __launch_bounds__(256) void merge_parts_kernel(const u64k* pq, int* idxb) {
  int g = blockIdx.x * blockDim.x + threadIdx.x;
  if (g >= NB * NN1) return;
  int b = g / NN1, n1 = g - b * NN1;
  for (int typ = 0; typ < 2; ++typ) {
    u64k A[8], B[8];
    loadq_(pq, b, 0, n1, typ, A);
    for (int p = 1; p < NPART; ++p) {
      loadq_(pq, b, p, n1, typ, B);
      merge8q_(A, B);
    }
    size_t ob = (size_t)g * 16 + typ * 8;
#pragma unroll
    for (int j = 0; j < 8; ++j) idxb[ob + j] = (int)(A[j] & 0xffffffffull);
  }
}

// ---------------- K5: fused GRU mapping v3 (block = 4 points, GEMM layers) ----------
__device__ __forceinline__ void gemm64_(const float* Ain, const float* Wt,
                                        int ty, int tx, float acc[4][4]) {
#pragma unroll
  for (int i = 0; i < 4; ++i)
#pragma unroll
    for (int j = 0; j < 4; ++j) acc[i][j] = 0.f;
#pragma unroll 8
  for (int c = 0; c < 64; ++c) {
    float4 a  = *(const float4*)&Ain[c * GPAD + ty * 4];
    float4 wv = *(const float4*)&Wt[c * 64 + tx * 4];
    acc[0][0] += a.x * wv.x; acc[0][1] += a.x * wv.y; acc[0][2] += a.x * wv.z; acc[0][3] += a.x * wv.w;
    acc[1][0] += a.y * wv.x; acc[1][1] += a.y * wv.y; acc[1][2] += a.y * wv.z; acc[1][3] += a.y * wv.w;
    acc[2][0] += a.z * wv.x; acc[2][1] += a.z * wv.y; acc[2][2] += a.z * wv.z; acc[2][3] += a.z * wv.w;
    acc[3][0] += a.w * wv.x; acc[3][1] += a.w * wv.y; acc[3][2] += a.w * wv.z; acc[3][3] += a.w * wv.w;
  }
}

__global__ __launch_bounds__(256, 4) void gru_kernel(
    const int* idxb, const float* x1t, const float* x2t,
    const float* p1r, const float* p1ro, const float* p1z,
    const float* p2r, const float* p2ro, const float* p2z,
    const float* wt,
    const float* br0, const float* br1, const float* br2,
    const float* bz0, const float* bz1, const float* bz2,
    const float* bh0, const float* bh1, const float* bh2,
    float* out) {
  __shared__ __align__(16) float A1[64 * GPAD];
  __shared__ __align__(16) float A2[64 * GPAD];
  __shared__ float Vpart[16 * 64];
  __shared__ float dxs[64 * 4];
  __shared__ int idxs[64];

  int t = threadIdx.x;
  int w = t >> 6, l = t & 63;
  int ty = t >> 4, tx = t & 15;
  int b = blockIdx.y;
  int n1i = blockIdx.x * 4 + w;
  int rowbase = b * NN1 + n1i;

  if (l < 16) {
    int gi = idxb[(size_t)rowbase * 16 + l];
    idxs[w * 16 + l] = gi;
    float4 x1v = ((const float4*)x1t)[rowbase];
    float4 x2v = ((const float4*)x2t)[b * NN2 + gi];
    dxs[(w * 16 + l) * 4 + 0] = x2v.x - x1v.x;
    dxs[(w * 16 + l) * 4 + 1] = x2v.y - x1v.y;
    dxs[(w * 16 + l) * 4 + 2] = x2v.z - x1v.z;
    dxs[(w * 16 + l) * 4 + 3] = 0.f;
  }
  float pr  = p1r [(size_t)rowbase * 64 + l];
  float pro = p1ro[(size_t)rowbase * 64 + l];
  float pz  = p1z [(size_t)rowbase * 64 + l];

  const float* Wr0t = wt + 6 * 4096;
  const float* Wr1t = wt + 7 * 4096;
  const float* Wr2t = wt + 8 * 4096;
  const float* Wz0t = wt + 9 * 4096;
  const float* Wz1t = wt + 10 * 4096;
  const float* Wz2t = wt + 11 * 4096;
  const float* Wh0t = wt + 12 * 4096;
  const float* Wh1t = wt + 13 * 4096;
  const float* Wh2t = wt + 14 * 4096;

  __syncthreads();

  // ---- L0 r -> A1[c=l][row] ----
  {
    float w0 = Wr0t[l], w1 = Wr0t[64 + l], w2 = Wr0t[128 + l], b0 = br0[l];
#pragma unroll
    for (int k = 0; k < 16; ++k) {
      int row = w * 16 + k;
      int gi = idxs[row];
      float g = p2r[((size_t)b * NN2 + gi) * 64 + l];
      float4 d = *(const float4*)&dxs[row * 4];
      A1[l * GPAD + row] = leaky_(b0 + pr + g + w0 * d.x + w1 * d.y + w2 * d.z);
    }
  }
  __syncthreads();

  float acc[4][4];

  // ---- r1 ----
  gemm64_(A1, Wr1t, ty, tx, acc);
  {
    const float* bq = &br1[tx * 4];
#pragma unroll
    for (int j = 0; j < 4; ++j) {
      float bb = bq[j];
#pragma unroll
      for (int i = 0; i < 4; ++i)
        A2[(tx * 4 + j) * GPAD + ty * 4 + i] = leaky_(acc[i][j] + bb);
    }
  }
  __syncthreads();

  // ---- r2 -> R3 in A1 ----
  gemm64_(A2, Wr2t, ty, tx, acc);
  {
    const float* bq = &br2[tx * 4];
#pragma unroll
    for (int j = 0; j < 4; ++j) {
      float bb = bq[j];
#pragma unroll
      for (int i = 0; i < 4; ++i)
        A1[(tx * 4 + j) * GPAD + ty * 4 + i] = sigm_(acc[i][j] + bb);
    }
  }
  __syncthreads();

  // ---- L0 z -> A2 ----
  {
    float w0 = Wz0t[l], w1 = Wz0t[64 + l], w2 = Wz0t[128 + l], b0 = bz0[l];
#pragma unroll
    for (int k = 0; k < 16; ++k) {
      int row = w * 16 + k;
      int gi = idxs[row];
      float g = p2ro[((size_t)b * NN2 + gi) * 64 + l];
      float4 d = *(const float4*)&dxs[row * 4];
      A2[l * GPAD + row] = leaky_(b0 + pz + g + w0 * d.x + w1 * d.y + w2 * d.z);
    }
  }
  __syncthreads();

  // ---- z1 -> max ----
  gemm64_(A2, Wz1t, ty, tx, acc);
  {
    const float* bq = &bz1[tx * 4];
#pragma unroll
    for (int j = 0; j < 4; ++j) {
      float bb = bq[j];
      float m = leaky_(acc[0][j] + bb);
      m = fmaxf(m, leaky_(acc[1][j] + bb));
      m = fmaxf(m, leaky_(acc[2][j] + bb));
      m = fmaxf(m, leaky_(acc[3][j] + bb));
      Vpart[ty * 64 + tx * 4 + j] = m;
    }
  }
  __syncthreads();
  float vm;
  {
    float v0 = Vpart[(w * 4 + 0) * 64 + l];
    float v1 = Vpart[(w * 4 + 1) * 64 + l];
    float v2 = Vpart[(w * 4 + 2) * 64 + l];
    float v3 = Vpart[(w * 4 + 3) * 64 + l];
    vm = fmaxf(fmaxf(v0, v1), fmaxf(v2, v3));
  }
  __syncthreads();
  float* Vv = Vpart;
  Vv[w * 64 + l] = vm;
  __syncthreads();
  float z3;
  {
    float a = bz2[l];
#pragma unroll 8
    for (int c = 0; c < 64; ++c) a += Vv[w * 64 + c] * Wz2t[c * 64 + l];
    z3 = sigm_(a);
  }

  // ---- L0 h -> A2 ----
  {
    float w0 = Wh0t[l], w1 = Wh0t[64 + l], w2 = Wh0t[128 + l], b0 = bh0[l];
#pragma unroll
    for (int k = 0; k < 16; ++k) {
      int row = w * 16 + k;
      int gi = idxs[row];
      float g = p2z[((size_t)b * NN2 + gi) * 64 + l];
      float4 d = *(const float4*)&dxs[row * 4];
      float r3 = A1[l * GPAD + row];
      A2[l * GPAD + row] = leaky_(b0 + r3 * pro + g + w0 * d.x + w1 * d.y + w2 * d.z);
    }
  }
  __syncthreads();

  // ---- h1 -> max ----
  gemm64_(A2, Wh1t, ty, tx, acc);
  {
    const float* bq = &bh1[tx * 4];
#pragma unroll
    for (int j = 0; j < 4; ++j) {
      float bb = bq[j];
      float m = leaky_(acc[0][j] + bb);
      m = fmaxf(m, leaky_(acc[1][j] + bb));
      m = fmaxf(m, leaky_(acc[2][j] + bb));
      m = fmaxf(m, leaky_(acc[3][j] + bb));
      Vpart[ty * 64 + tx * 4 + j] = m;
    }
  }
  __syncthreads();
  {
    float v0 = Vpart[(w * 4 + 0) * 64 + l];
    float v1 = Vpart[(w * 4 + 1) * 64 + l];
    float v2 = Vpart[(w * 4 + 2) * 64 + l];
    float v3 = Vpart[(w * 4 + 3) * 64 + l];
    vm = fmaxf(fmaxf(v0, v1), fmaxf(v2, v3));
  }
  __syncthreads();
  Vv[w * 64 + l] = vm;
  __syncthreads();
  float h3;
  {
    float a = bh2[l];
#pragma unroll 8
    for (int c = 0; c < 64; ++c) a += Vv[w * 64 + c] * Wh2t[c * 64 + l];
    h3 = leaky_(a);
  }

  out[((size_t)b * 64 + l) * NN1 + n1i] = (1.0f - z3) * pro + z3 * h3;
}

extern "C" void kernel_launch(void* const* d_in, const int* in_sizes, int n_in,
                              void* d_out, int out_size, void* d_ws, size_t ws_size,
                              hipStream_t stream) {
  (void)in_sizes; (void)n_in; (void)out_size; (void)ws_size;
  const float* xyz1    = (const float*)d_in[0];
  const float* xyz2    = (const float*)d_in[1];
  const float* points1 = (const float*)d_in[2];
  const float* points2 = (const float*)d_in[3];
  const float* knn1    = (const float*)d_in[4];
  const float* knn2    = (const float*)d_in[5];
  const float* Wfr   = (const float*)d_in[6];
  const float* Wfro  = (const float*)d_in[7];
  const float* Wfz   = (const float*)d_in[8];
  const float* Wfr2  = (const float*)d_in[9];
  const float* Wfro2 = (const float*)d_in[10];
  const float* Wfz2  = (const float*)d_in[11];
  const float* Wr0 = (const float*)d_in[12]; const float* br0 = (const float*)d_in[13];
  const float* Wr1 = (const float*)d_in[14]; const float* br1 = (const float*)d_in[15];
  const float* Wr2 = (const float*)d_in[16]; const float* br2 = (const float*)d_in[17];
  const float* Wz0 = (const float*)d_in[18]; const float* bz0 = (const float*)d_in[19];
  const float* Wz1 = (const float*)d_in[20]; const float* bz1 = (const float*)d_in[21];
  const float* Wz2 = (const float*)d_in[22]; const float* bz2 = (const float*)d_in[23];
  const float* Wh0 = (const float*)d_in[24]; const float* bh0 = (const float*)d_in[25];
  const float* Wh1 = (const float*)d_in[26]; const float* bh1 = (const float*)d_in[27];
  const float* Wh2 = (const float*)d_in[28]; const float* bh2 = (const float*)d_in[29];

  float* W = (float*)d_ws;
  size_t o = 0;
  float* f1T = W + o; o += (size_t)NB * NN1 * 64;
  float* f2T = W + o; o += (size_t)NB * NN2 * 64;
  float* x1t = W + o; o += (size_t)NB * NN1 * 4;
  float* x2t = W + o; o += (size_t)NB * NN2 * 4;
  float* p1r = W + o; o += (size_t)NB * NN1 * 64;
  float* p1ro = W + o; o += (size_t)NB * NN1 * 64;
  float* p1z = W + o; o += (size_t)NB * NN1 * 64;
  float* p2r = W + o; o += (size_t)NB * NN2 * 64;
  float* p2ro = W + o; o += (size_t)NB * NN2 * 64;
  float* p2z = W + o; o += (size_t)NB * NN2 * 64;
  float* wt = W + o; o += (size_t)15 * 4096;
  u64k* pq = (u64k*)(W + o); o += (size_t)2 * NB * NPART * NN1 * 16;
  int* idxb = (int*)(W + o); o += (size_t)NB * NN1 * 16;

  float* out = (float*)d_out;

  hipLaunchKernelGGL(prep_w_kernel, dim3(15), dim3(256), 0, stream,
                     Wfr, Wfro, Wfz, Wfr2, Wfro2, Wfz2,
                     Wr0, Wr1, Wr2, Wz0, Wz1, Wz2, Wh0, Wh1, Wh2, wt);
  hipLaunchKernelGGL(prep_side_kernel, dim3(NN1 / 64, NB), dim3(256), 0, stream,
                     knn1, xyz1, f1T, x1t, NN1);
  hipLaunchKernelGGL(prep_side_kernel, dim3(NN2 / 64, NB), dim3(256), 0, stream,
                     knn2, xyz2, f2T, x2t, NN2);
  hipLaunchKernelGGL(fuse_kernel, dim3(NN1 / 4, NB), dim3(256), 0, stream,
                     points1, wt + 0 * 4096, wt + 1 * 4096, wt + 2 * 4096,
                     p1r, p1ro, p1z, NN1);
  hipLaunchKernelGGL(fuse_kernel, dim3(NN2 / 4, NB), dim3(256), 0, stream,
                     points2, wt + 3 * 4096, wt + 4 * 4096, wt + 5 * 4096,
                     p2r, p2ro, p2z, NN2);
  hipLaunchKernelGGL(knn_kernel, dim3(NN1 / 64, NPART, NB), dim3(256), 0, stream,
                     f1T, f2T, x1t, x2t, pq);
  hipLaunchKernelGGL(merge_parts_kernel, dim3((NB * NN1 + 255) / 256), dim3(256), 0, stream,
                     pq, idxb);
  hipLaunchKernelGGL(gru_kernel, dim3(NN1 / 4, NB), dim3(256), 0, stream,
                     idxb, x1t, x2t, p1r, p1ro, p1z, p2r, p2ro, p2z, wt,
                     br0, br1, br2, bz0, bz1, bz2, bh0, bh1, bh2, out);
}